// Round 12
// baseline (253.663 us; speedup 1.0000x reference)
//
#include <hip/hip_runtime.h>

// SosModel: cascade of 4 biquads over T=32768, per (batch,channel); B=16, C=64.
// Wave = one (batch, 64-step chunk), uniform WARM=96 for ALL chunks (pre-t0
// rows clamped to row 0 and masked by a wave-uniform 0.0 -> exact zero-input
// warm-up; k>=2 truncation ~0.9^96*gain ~1e-3 << 2.6e-2). lane == channel.
//
// R12 == R10 resubmitted verbatim (3rd attempt): R10/R11 died at container
// acquisition ("MI355X container failed twice" -- identical infra signature
// to R6/R7, which cleared on the 3rd submit as R8). Failure occurs before
// kernel execution; kernel is straight-line unrolled, no barriers, BLOCK=1024
// legal, launch_bounds(1024,4) caps VGPR 128 >> ~56 needed.
//
// THEORY (occupancy/residency): five structures plateau at 90-95us /
// ~3.3 TB/s with OccupancyPercent ~33% (10.6/32 waves/CU); R3's spill
// variant proved 73% occupancy is reachable with this grid. ~2.65 waves/SIMD
// each ~half-stalled reproduces VALU~45% + HBM~50% with nothing saturated.
// At full residency: VALU floor ~18us, BW floor ~45us -> expect 55-70us.
//  Lever 1: BLOCK 256->1024 (512 blocks, 2 blocks/CU) -> 16 waves placed
//           atomically per block; target 32 waves/CU (VGPR 56: 8/SIMD fits).
//  Lever 2: bijective XCD-chunked swizzle (512%8==0): each XCD owns a
//           contiguous 2-batch slab -> L2-local overlap re-reads.
// Counter read: occupancy jumps -> residency was the wall. Occupancy still
// ~33% -> ~3.3 TB/s is this pattern's supply ceiling (roofline case).

#define TLEN  32768
#define CCH   64
#define NSEC  4
#define CHUNK 64
#define WARM  96

#define NCHUNKS (TLEN / CHUNK)          // 512
#define NWAVES  (16 * NCHUNKS)          // 8192
#define BLOCK   1024
#define NBLOCKS (NWAVES * 64 / BLOCK)   // 512 -> 2 blocks/CU, 32 waves/CU

// Load the 8 rows of group G into register buffer NB (8 x 256B dword loads).
// Low clamp: pre-t0 warm rows (masked to zero at consume -> exact).
// High clamp: only the last chunk's pipeline tail; clamped rows feed only
// section-0..2 state for times > T-1, which never reaches a stored output.
#define ISSUE(NB, G) do {                                                     \
    int rb_ = s0 + 8 * (G);                                                   \
    rb_ = rb_ < 0 ? 0 : rb_;                                                  \
    rb_ = rb_ > TLEN - 8 ? TLEN - 8 : rb_;                                    \
    const float* __restrict__ p_ = xb + (size_t)rb_ * CCH;                    \
    NB[0] = p_[0 * CCH]; NB[1] = p_[1 * CCH];                                 \
    NB[2] = p_[2 * CCH]; NB[3] = p_[3 * CCH];                                 \
    NB[4] = p_[4 * CCH]; NB[5] = p_[5 * CCH];                                 \
    NB[6] = p_[6 * CCH]; NB[7] = p_[7 * CCH];                                 \
} while (0)

// Skewed-pipeline cascade step: section s processes time s0+i-s at iter i.
// Loop-carried dependency = 1 FMA per section (y1 -> o).
#define FBODY(xin)                                                            \
    const float i0 = (xin), i1 = lat1, i2 = lat2, i3 = lat3;                  \
    const float p0 = fmaf(cb0[0], i0, fmaf(cb1[0], x1[0], cb2[0] * x2[0]));   \
    const float p1 = fmaf(cb0[1], i1, fmaf(cb1[1], x1[1], cb2[1] * x2[1]));   \
    const float p2 = fmaf(cb0[2], i2, fmaf(cb1[2], x1[2], cb2[2] * x2[2]));   \
    const float p3 = fmaf(cb0[3], i3, fmaf(cb1[3], x1[3], cb2[3] * x2[3]));   \
    const float o0 = fmaf(ca1[0], y1v[0], fmaf(ca2[0], y2v[0], p0));          \
    const float o1 = fmaf(ca1[1], y1v[1], fmaf(ca2[1], y2v[1], p1));          \
    const float o2 = fmaf(ca1[2], y1v[2], fmaf(ca2[2], y2v[2], p2));          \
    const float o3 = fmaf(ca1[3], y1v[3], fmaf(ca2[3], y2v[3], p3));          \
    x2[0] = x1[0]; x1[0] = i0;  y2v[0] = y1v[0]; y1v[0] = o0;                 \
    x2[1] = x1[1]; x1[1] = i1;  y2v[1] = y1v[1]; y1v[1] = o1;                 \
    x2[2] = x1[2]; x1[2] = i2;  y2v[2] = y1v[2]; y1v[2] = o2;                 \
    x2[3] = x1[3]; x1[3] = i3;  y2v[3] = y1v[3]; y1v[3] = o3;                 \
    lat1 = o0; lat2 = o1; lat3 = o2;

#define STEP_NS(xin)    do { FBODY(xin); (void)o3; } while (0)
#define STEP_Y(xin, R)  do { FBODY(xin); yout[R] = o3; } while (0)   // R literal

// Warm group g (0..11): prefetch L(g+2), consume CB masked (wave-uniform 0/1).
#define WG(CB, NB, g) do {                                                    \
    ISSUE(NB, (g) + 2);                                                       \
    const float wm_ = (s0 + 8 * (g) >= 0) ? 1.0f : 0.0f;                      \
    STEP_NS(CB[0] * wm_); STEP_NS(CB[1] * wm_);                               \
    STEP_NS(CB[2] * wm_); STEP_NS(CB[3] * wm_);                               \
    STEP_NS(CB[4] * wm_); STEP_NS(CB[5] * wm_);                               \
    STEP_NS(CB[6] * wm_); STEP_NS(CB[7] * wm_);                               \
} while (0)

// Full group: prefetch L(g+2), 8 steps -> yout[R0..R0+7].
#define SG(CB, NB, g, R0) do {                                                \
    ISSUE(NB, (g) + 2);                                                       \
    STEP_Y(CB[0], (R0) + 0); STEP_Y(CB[1], (R0) + 1);                         \
    STEP_Y(CB[2], (R0) + 2); STEP_Y(CB[3], (R0) + 3);                         \
    STEP_Y(CB[4], (R0) + 4); STEP_Y(CB[5], (R0) + 5);                         \
    STEP_Y(CB[6], (R0) + 6); STEP_Y(CB[7], (R0) + 7);                         \
} while (0)

__global__ __launch_bounds__(BLOCK, 4) void sos_kernel(const float* __restrict__ x,
                                                       const float* __restrict__ sos,
                                                       float* __restrict__ out) {
    const int lane = threadIdx.x & 63;                    // channel
    // Bijective XCD-chunked swizzle (NBLOCKS=512, 512%8==0): consecutive
    // hardware blockIdx round-robin across XCDs; remap so XCD j owns the
    // contiguous virtual range [j*64, (j+1)*64) -> contiguous 16MB slab.
    const int vb   = (blockIdx.x & 7) * (NBLOCKS / 8) + (blockIdx.x >> 3);
    const int wid  = __builtin_amdgcn_readfirstlane(
                         vb * (BLOCK >> 6) + (threadIdx.x >> 6));
    const int b    = wid >> 9;                            // wid / NCHUNKS
    const int k    = wid & (NCHUNKS - 1);
    const int t0   = k * CHUNK;
    const int s0   = t0 - WARM;                           // uniform for ALL waves

    const float* __restrict__ xb = x + (size_t)b * TLEN * CCH + lane;
    float* __restrict__ py = out + ((size_t)b * TLEN + t0) * CCH + lane;

    // Prime the distance-2 pipeline.
    float Af[8], Bf[8], Cf[8];
    ISSUE(Af, 0);
    ISSUE(Bf, 1);

    // Coefficients (wave-uniform); honor /a0 though a0==1 here.
    float cb0[NSEC], cb1[NSEC], cb2[NSEC], ca1[NSEC], ca2[NSEC];
    float x1[NSEC], x2[NSEC], y1v[NSEC], y2v[NSEC];
#pragma unroll
    for (int s = 0; s < NSEC; ++s) {
        const float inva = 1.0f / sos[s * 6 + 3];
        cb0[s] =  sos[s * 6 + 0] * inva;
        cb1[s] =  sos[s * 6 + 1] * inva;
        cb2[s] =  sos[s * 6 + 2] * inva;
        ca1[s] = -sos[s * 6 + 4] * inva;
        ca2[s] = -sos[s * 6 + 5] * inva;
        x1[s] = x2[s] = y1v[s] = y2v[s] = 0.0f;
    }
    float lat1 = 0.0f, lat2 = 0.0f, lat3 = 0.0f;          // inter-section latches

    float yout[64];                                       // all indices literal

    // Buffer of L(h) = h % 3 (Af=0, Bf=1, Cf=2); group h consumes h%3 and
    // issues L(h+2) into (h+2)%3 (freed last group).
    // Phase 1: warm groups 0..11 (i = 0..95), masked, no outputs.
    WG(Af, Cf, 0);  WG(Bf, Af, 1);  WG(Cf, Bf, 2);
    WG(Af, Cf, 3);  WG(Bf, Af, 4);  WG(Cf, Bf, 5);
    WG(Af, Cf, 6);  WG(Bf, Af, 7);  WG(Cf, Bf, 8);
    WG(Af, Cf, 9);  WG(Bf, Af, 10); WG(Cf, Bf, 11);

    // Phase 2: group 12 (i=96..103): j=0..2 warm tail, j=3..7 -> yout[0..4].
    {
        ISSUE(Cf, 14);
        STEP_NS(Af[0]); STEP_NS(Af[1]); STEP_NS(Af[2]);
        STEP_Y(Af[3], 0); STEP_Y(Af[4], 1); STEP_Y(Af[5], 2);
        STEP_Y(Af[6], 3); STEP_Y(Af[7], 4);
    }

    // Phase 3: groups 13..18 -> yout[5..52] (R0 = 8*(g-12)-3).
    SG(Bf, Af, 13, 5);
    SG(Cf, Bf, 14, 13);
    SG(Af, Cf, 15, 21);
    SG(Bf, Af, 16, 29);
    SG(Cf, Bf, 17, 37);
    SG(Af, Cf, 18, 45);      // issues L20 -> Cf (last load)

    // Group 19 (no prefetch): -> yout[53..60].
    {
        STEP_Y(Bf[0], 53); STEP_Y(Bf[1], 54); STEP_Y(Bf[2], 55);
        STEP_Y(Bf[3], 56); STEP_Y(Bf[4], 57); STEP_Y(Bf[5], 58);
        STEP_Y(Bf[6], 59); STEP_Y(Bf[7], 60);
    }
    // Group 20: j=0..2 (i=160..162) -> yout[61..63].
    {
        STEP_Y(Cf[0], 61); STEP_Y(Cf[1], 62); STEP_Y(Cf[2], 63);
    }

    // Epilogue stores. (R8 showed the compiler sinks these into the main
    // loop; R9 showed preventing that is WORSE. So let it.)
#pragma unroll
    for (int r = 0; r < 64; ++r) {
        py[(size_t)r * CCH] = yout[r];
    }
}

extern "C" void kernel_launch(void* const* d_in, const int* in_sizes, int n_in,
                              void* d_out, int out_size, void* d_ws, size_t ws_size,
                              hipStream_t stream) {
    const float* x   = (const float*)d_in[0];   // [B, T, C] fp32
    const float* sos = (const float*)d_in[1];   // [S, 6] fp32
    float* out = (float*)d_out;                 // [B, T, C] fp32
    sos_kernel<<<NBLOCKS, BLOCK, 0, stream>>>(x, sos, out);
}